// Round 1
// baseline (4572.486 us; speedup 1.0000x reference)
//
#include <hip/hip_runtime.h>
#include <math.h>

// Problem constants
#define T_STEPS 256
#define BB 8
#define NSTATE 64
#define DD 80
#define PP 256
#define HH 512
#define OO 512
#define NPARAM 161   // 2*D+1
#define NPADP 192    // padded param dim for LDS tiles
#define PLS 171      // padded row stride for params in LDS (bank spread)
#define NEG_INF_F (-1000000.0f)

__device__ __forceinline__ float sigmoidf_(float x) { return 1.0f / (1.0f + __expf(-x)); }

// ---------------------------------------------------------------------------
// prep kernels
// ---------------------------------------------------------------------------
__global__ void ar_fill(const float* __restrict__ mels, float* __restrict__ ar) {
  int idx = blockIdx.x * 256 + threadIdx.x;
  if (idx >= T_STEPS * BB * DD) return;
  int d = idx % DD; int r = idx / DD; int b = r % BB; int t = r / BB;
  // ar[t][b][d] = t==0 ? 0 : mels[b][d][t-1]
  ar[idx] = (t == 0) ? 0.0f : mels[(b * DD + d) * T_STEPS + (t - 1)];
}

__global__ void w2t_fill(const float* __restrict__ w2, float* __restrict__ w2t) {
  int idx = blockIdx.x * 256 + threadIdx.x;
  if (idx >= OO * NPADP) return;
  int p = idx % NPADP; int k = idx / NPADP;
  w2t[idx] = (p < NPARAM) ? w2[p * OO + k] : 0.0f;  // w2t[k][p] = out_w2[p][k]
}

__global__ void bar_init(int* bar) {
  int i = threadIdx.x;
  if (i < 128) bar[i] = 0;
}

// ---------------------------------------------------------------------------
// generic tiled fp32 GEMM:  C[m][n] = act( sum_k A[m][aoff+k]*B[n][boff+k] + bias )
// M,N multiples of 64. Grid (N/64, M/64), 256 threads, 4x4 per-thread tile.
// tstore=1: scatter-store for ziT layout [b][o][nstate] (M must be B*NSTATE, N=OO).
// ---------------------------------------------------------------------------
__global__ __launch_bounds__(256)
void gemm_nt(const float* __restrict__ A, int lda, int aoff,
             const float* __restrict__ Bw, int ldb, int boff,
             const float* __restrict__ bias1, const float* __restrict__ bias2,
             float* __restrict__ C, int M, int N, int K, int relu, int tstore)
{
  __shared__ float As[32][64];   // [kk][mm]
  __shared__ float Bs[32][64];   // [kk][nn]
  const int tid = threadIdx.x;
  const int m0 = blockIdx.y * 64, n0 = blockIdx.x * 64;
  const int tm = tid & 15, tn = tid >> 4;
  float acc[4][4] = {{0.f,0.f,0.f,0.f},{0.f,0.f,0.f,0.f},{0.f,0.f,0.f,0.f},{0.f,0.f,0.f,0.f}};

  for (int k0 = 0; k0 < K; k0 += 32) {
#pragma unroll
    for (int half = 0; half < 2; ++half) {
      int mm = (tid >> 3) + half * 32;
      int kk = (tid & 7) * 4;
      const float* ap = &A[(size_t)(m0 + mm) * lda + aoff + k0 + kk];
      float4 av;
      if (k0 + kk + 3 < K) {
        av = *(const float4*)ap;
      } else {
        av.x = (k0 + kk + 0 < K) ? ap[0] : 0.f;
        av.y = (k0 + kk + 1 < K) ? ap[1] : 0.f;
        av.z = (k0 + kk + 2 < K) ? ap[2] : 0.f;
        av.w = (k0 + kk + 3 < K) ? ap[3] : 0.f;
      }
      As[kk + 0][mm] = av.x; As[kk + 1][mm] = av.y;
      As[kk + 2][mm] = av.z; As[kk + 3][mm] = av.w;
      const float* bp = &Bw[(size_t)(n0 + mm) * ldb + boff + k0 + kk];
      float4 bv;
      if (k0 + kk + 3 < K) {
        bv = *(const float4*)bp;
      } else {
        bv.x = (k0 + kk + 0 < K) ? bp[0] : 0.f;
        bv.y = (k0 + kk + 1 < K) ? bp[1] : 0.f;
        bv.z = (k0 + kk + 2 < K) ? bp[2] : 0.f;
        bv.w = (k0 + kk + 3 < K) ? bp[3] : 0.f;
      }
      Bs[kk + 0][mm] = bv.x; Bs[kk + 1][mm] = bv.y;
      Bs[kk + 2][mm] = bv.z; Bs[kk + 3][mm] = bv.w;
    }
    __syncthreads();
#pragma unroll
    for (int kk = 0; kk < 32; ++kk) {
      float4 a4 = *(const float4*)&As[kk][tm * 4];
      float4 b4 = *(const float4*)&Bs[kk][tn * 4];
      float av[4] = {a4.x, a4.y, a4.z, a4.w};
      float bvv[4] = {b4.x, b4.y, b4.z, b4.w};
#pragma unroll
      for (int i = 0; i < 4; ++i)
#pragma unroll
        for (int j = 0; j < 4; ++j)
          acc[i][j] += av[i] * bvv[j];
    }
    __syncthreads();
  }

  float bj[4];
#pragma unroll
  for (int j = 0; j < 4; ++j) {
    int n = n0 + tn * 4 + j;
    float bv = 0.f;
    if (bias1) bv += bias1[n];
    if (bias2) bv += bias2[n];
    bj[j] = bv;
  }
  if (!tstore) {
#pragma unroll
    for (int i = 0; i < 4; ++i) {
      int m = m0 + tm * 4 + i;
      float4 v;
      v.x = acc[i][0] + bj[0]; v.y = acc[i][1] + bj[1];
      v.z = acc[i][2] + bj[2]; v.w = acc[i][3] + bj[3];
      if (relu) {
        v.x = fmaxf(v.x, 0.f); v.y = fmaxf(v.y, 0.f);
        v.z = fmaxf(v.z, 0.f); v.w = fmaxf(v.w, 0.f);
      }
      *(float4*)&C[(size_t)m * N + n0 + tn * 4] = v;
    }
  } else {
    // ziT[b][o][ns]: m = b*64+ns, n = o
#pragma unroll
    for (int i = 0; i < 4; ++i) {
      int m = m0 + tm * 4 + i;
      int bb = m >> 6, ns = m & 63;
#pragma unroll
      for (int j = 0; j < 4; ++j) {
        int o = n0 + tn * 4 + j;
        float v = acc[i][j] + bj[j];
        if (relu) v = fmaxf(v, 0.f);
        C[((size_t)bb * OO + o) * NSTATE + ns] = v;
      }
    }
  }
}

// ---------------------------------------------------------------------------
// persistent sequential LSTM: 128 blocks x 128 threads, grid barrier per step.
// block owns 4 h-units (j0..j0+3) x 4 gates x 8 batches; w_hh slice in LDS.
// gates[t] = gates_x[t] + h[t-1] @ w_hh^T ; c,h update; h broadcast via
// agent-scope atomics (per-XCD L2 not coherent).
// ---------------------------------------------------------------------------
__global__ __launch_bounds__(128)
void lstm_seq(const float* __restrict__ w_hh, const float* __restrict__ gates_x,
              float* __restrict__ h_all, int* __restrict__ bar)
{
  __shared__ float wl[16][516];  // 16 gate-rows x 512 (+4 pad: bank spread, 16B align)
  __shared__ float hl[8][516];   // h[b][k]
  __shared__ float gl[128];
  const int tid = threadIdx.x;
  const int blk = blockIdx.x;        // 0..127
  const int j0 = blk * 4;
  const int g  = tid >> 5;           // gate 0..3 (i,f,g,o)
  const int jl = (tid >> 3) & 3;     // local j 0..3
  const int b  = tid & 7;            // batch
  const int rloc = g * 4 + jl;
  const int nb = gridDim.x;

  for (int r = 0; r < 16; ++r) {
    int gg = r >> 2, jj = r & 3;
    const float* src = &w_hh[((size_t)gg * HH + j0 + jj) * HH];
    for (int k = tid; k < HH; k += 128) wl[r][k] = src[k];
  }
  float c_reg = 0.f;

  for (int t = 0; t < T_STEPS; ++t) {
    if (t == 0) {
      for (int i = tid; i < BB * HH; i += 128) hl[i >> 9][i & 511] = 0.f;
    } else {
      const double* hsrc = (const double*)(h_all + (size_t)(t - 1) * BB * HH);
      for (int i = tid; i < BB * HH / 2; i += 128) {
        union { double d; float f[2]; } u;
        u.d = __hip_atomic_load(hsrc + i, __ATOMIC_RELAXED, __HIP_MEMORY_SCOPE_AGENT);
        int base = i * 2;
        hl[base >> 9][base & 511] = u.f[0];
        hl[base >> 9][(base & 511) + 1] = u.f[1];
      }
    }
    __syncthreads();

    float acc = gates_x[((size_t)t * BB + b) * (4 * HH) + g * HH + j0 + jl];
#pragma unroll 8
    for (int k4 = 0; k4 < 128; ++k4) {
      float4 w4 = *(const float4*)&wl[rloc][k4 * 4];
      float4 h4 = *(const float4*)&hl[b][k4 * 4];
      acc += w4.x * h4.x + w4.y * h4.y + w4.z * h4.z + w4.w * h4.w;
    }
    gl[tid] = acc;
    __syncthreads();

    if (tid < 32) {
      float iv = gl[tid], fv = gl[32 + tid], gv = gl[64 + tid], ov = gl[96 + tid];
      float ct = sigmoidf_(fv) * c_reg + sigmoidf_(iv) * tanhf(gv);
      c_reg = ct;
      float h = sigmoidf_(ov) * tanhf(ct);
      int bb = tid & 7, jj = (tid >> 3) & 3;
      __hip_atomic_store(&h_all[((size_t)t * BB + bb) * HH + j0 + jj], h,
                         __ATOMIC_RELAXED, __HIP_MEMORY_SCOPE_AGENT);
    }
    __syncthreads();  // drains vmcnt -> h stores retired at coherence point

    if (tid == 0) {
      __hip_atomic_fetch_add(&bar[(blk & 3) * 32], 1, __ATOMIC_ACQ_REL, __HIP_MEMORY_SCOPE_AGENT);
      int target = (t + 1) * nb;
      for (;;) {
        int s = __hip_atomic_load(&bar[0],  __ATOMIC_ACQUIRE, __HIP_MEMORY_SCOPE_AGENT)
              + __hip_atomic_load(&bar[32], __ATOMIC_ACQUIRE, __HIP_MEMORY_SCOPE_AGENT)
              + __hip_atomic_load(&bar[64], __ATOMIC_ACQUIRE, __HIP_MEMORY_SCOPE_AGENT)
              + __hip_atomic_load(&bar[96], __ATOMIC_ACQUIRE, __HIP_MEMORY_SCOPE_AGENT);
        if (s >= target) break;
        __builtin_amdgcn_s_sleep(4);
      }
    }
    __syncthreads();
  }
}

// ---------------------------------------------------------------------------
// fused output net + emission, block per (t,b):
// hid = relu(hv[t,b,:] + ziT[b,:,n]); params = hid @ w2t + b2;
// emission (Gaussian logpdf sum over D, masked), trans log-sigmoids.
// ---------------------------------------------------------------------------
__global__ __launch_bounds__(256)
void outnet(const float* __restrict__ hv, const float* __restrict__ ziT,
            const float* __restrict__ w2t, const float* __restrict__ b2,
            const float* __restrict__ mels, const int* __restrict__ inputs_len,
            float* __restrict__ em_out, float* __restrict__ lsn_out,
            float* __restrict__ lsp_out)
{
  __shared__ float smem[10944 + OO + DD];
  float* w2s = smem;            // [32][192] (union with pl)
  float* hs  = smem + 6144;     // [32][64]
  float* pl  = smem;            // [64][PLS] after GEMM loop
  float* hvs = smem + 10944;    // [512]
  float* xts = smem + 10944 + OO;  // [80]
  const int tid = threadIdx.x;
  const int tb = blockIdx.x;
  const int t = tb >> 3, b = tb & 7;

  if (tid < 128) *(float4*)&hvs[tid * 4] = *(const float4*)&hv[(size_t)tb * OO + tid * 4];
  if (tid < DD) xts[tid] = mels[(b * DD + tid) * T_STEPS + t];
  __syncthreads();

  const int tm = tid & 15, tn = tid >> 4;
  float acc[4][12];
#pragma unroll
  for (int i = 0; i < 4; ++i)
#pragma unroll
    for (int j = 0; j < 12; ++j) acc[i][j] = 0.f;

  for (int kc = 0; kc < 16; ++kc) {
    const int k0 = kc * 32;
    for (int i4 = tid; i4 < 1536; i4 += 256)
      *(float4*)&w2s[i4 * 4] = *(const float4*)&w2t[(size_t)k0 * NPADP + i4 * 4];
    const float* zsrc = ziT + (size_t)b * OO * NSTATE + (size_t)k0 * NSTATE;
    for (int i4 = tid; i4 < 512; i4 += 256) {
      float4 z = *(const float4*)&zsrc[i4 * 4];
      float hh = hvs[k0 + (i4 >> 4)];
      float4 r;
      r.x = fmaxf(z.x + hh, 0.f); r.y = fmaxf(z.y + hh, 0.f);
      r.z = fmaxf(z.z + hh, 0.f); r.w = fmaxf(z.w + hh, 0.f);
      *(float4*)&hs[i4 * 4] = r;
    }
    __syncthreads();
#pragma unroll
    for (int kk = 0; kk < 32; ++kk) {
      float4 a4 = *(const float4*)&hs[kk * 64 + tm * 4];
      float4 wa = *(const float4*)&w2s[kk * NPADP + tn * 12];
      float4 wb = *(const float4*)&w2s[kk * NPADP + tn * 12 + 4];
      float4 wc = *(const float4*)&w2s[kk * NPADP + tn * 12 + 8];
      float av[4]  = {a4.x, a4.y, a4.z, a4.w};
      float wv[12] = {wa.x, wa.y, wa.z, wa.w, wb.x, wb.y, wb.z, wb.w,
                      wc.x, wc.y, wc.z, wc.w};
#pragma unroll
      for (int i = 0; i < 4; ++i)
#pragma unroll
        for (int j = 0; j < 12; ++j)
          acc[i][j] += av[i] * wv[j];
    }
    __syncthreads();
  }

  // params -> LDS (union region; all GEMM reads done)
#pragma unroll
  for (int i = 0; i < 4; ++i)
#pragma unroll
    for (int j = 0; j < 12; ++j) {
      int p = tn * 12 + j;
      if (p < NPARAM) pl[(tm * 4 + i) * PLS + p] = acc[i][j] + b2[p];
    }
  __syncthreads();

  const int ne = tid >> 2, dq = tid & 3;
  float s = 0.f;
  for (int d = dq * 20; d < dq * 20 + 20; ++d) {
    float mean = pl[ne * PLS + d];
    float sp   = pl[ne * PLS + 80 + d];
    float x = xts[d];
    float sf = (sp > 20.f) ? sp : log1pf(__expf(sp));
    float sd = fmaxf(sf, 0.001f);
    float zz = (x - mean) / sd;
    s += -0.5f * zz * zz - __logf(sd) - 0.91893853320467274f;  // 0.5*log(2*pi)
  }
  s += __shfl_xor(s, 1);
  s += __shfl_xor(s, 2);
  if (dq == 0) {
    int ilen = inputs_len[b];
    em_out[(size_t)tb * NSTATE + ne] = (ne < ilen) ? s : 0.f;
    float tv = pl[ne * PLS + 160];
    lsp_out[(size_t)tb * NSTATE + ne] = __logf(fmaxf(sigmoidf_(tv), 1e-4f));
    lsn_out[(size_t)tb * NSTATE + ne] = __logf(fmaxf(sigmoidf_(-tv), 1e-4f));
  }
}

// ---------------------------------------------------------------------------
// sequential HMM forward scan: 1 block, wave per batch, alpha in registers.
// ---------------------------------------------------------------------------
__global__ __launch_bounds__(512)
void hmm_scan(const float* __restrict__ em, const float* __restrict__ lsn,
              const float* __restrict__ lsp, const int* __restrict__ inputs_len,
              const int* __restrict__ mel_lens, float* __restrict__ out)
{
  const int tid = threadIdx.x;
  const int b = tid >> 6, n = tid & 63;
  const int ilen = inputs_len[b], mlen = mel_lens[b];
  const bool mask = n < ilen;
  float alpha = 0.f, slc = 0.f, la = NEG_INF_F, llsp = 0.f;

  for (int t = 0; t < T_STEPS; ++t) {
    size_t base = ((size_t)t * BB + b) * NSTATE + n;
    float e = em[base], ln_ = lsn[base], lp_ = lsp[base];
    float at;
    if (t == 0) {
      at = ((n == 0) ? 0.f : NEG_INF_F) + e;
    } else {
      float stay = alpha + ln_;
      float lvs = alpha + lp_;
      float lv = __shfl_up(lvs, 1, 64);
      if (n == 0) lv = NEG_INF_F;
      float mx = fmaxf(stay, lv), mn = fminf(stay, lv);
      float tt = mask ? (mx + log1pf(__expf(mn - mx))) : NEG_INF_F;
      at = e + tt;
    }
    float m = at;
#pragma unroll
    for (int off = 1; off < 64; off <<= 1) m = fmaxf(m, __shfl_xor(m, off));
    float es = __expf(at - m);
#pragma unroll
    for (int off = 1; off < 64; off <<= 1) es += __shfl_xor(es, off);
    float logc = m + __logf(es);
    alpha = at - logc;
    if (t < mlen) slc += logc;
    if (t == mlen - 1) { la = mask ? alpha : NEG_INF_F; llsp = lp_; }
  }

  float v = la + ((n == ilen - 1) ? llsp : NEG_INF_F);
  float m = v;
#pragma unroll
  for (int off = 1; off < 64; off <<= 1) m = fmaxf(m, __shfl_xor(m, off));
  float es = __expf(v - m);
#pragma unroll
  for (int off = 1; off < 64; off <<= 1) es += __shfl_xor(es, off);
  float sfin = m + __logf(es);
  if (n == 0) out[b] = slc + sfin;
}

// ---------------------------------------------------------------------------
extern "C" void kernel_launch(void* const* d_in, const int* in_sizes, int n_in,
                              void* d_out, int out_size, void* d_ws, size_t ws_size,
                              hipStream_t stream)
{
  const float* inputs    = (const float*)d_in[0];
  const float* mels      = (const float*)d_in[1];
  const float* prenet_w1 = (const float*)d_in[2];
  const float* prenet_w2 = (const float*)d_in[3];
  const float* w_ih      = (const float*)d_in[4];
  const float* w_hh      = (const float*)d_in[5];
  const float* b_ih      = (const float*)d_in[6];
  const float* b_hh      = (const float*)d_in[7];
  const float* out_w1    = (const float*)d_in[8];
  const float* out_b1    = (const float*)d_in[9];
  const float* out_w2    = (const float*)d_in[10];
  const float* out_b2    = (const float*)d_in[11];
  const int* inputs_len  = (const int*)d_in[12];
  const int* mel_lens    = (const int*)d_in[13];

  float* ws = (float*)d_ws;
  float* ar      = ws;                       // T*B*D      = 163840
  float* p1      = ar + 163840;              // T*B*P      = 524288
  float* p2      = p1 + 524288;              // T*B*P      = 524288
  float* gates_x = p2 + 524288;              // T*B*4H     = 4194304
  float* ziT     = gates_x + 4194304;        // B*O*N      = 262144
  float* w2t     = ziT + 262144;             // O*NPADP    = 98304
  float* h_all   = w2t + 98304;              // T*B*H      = 1048576
  float* hv      = h_all + 1048576;          // T*B*O      = 1048576
  float* em      = hv + 1048576;             // T*B*N      = 131072
  float* lsn     = em + 131072;              // T*B*N      = 131072
  float* lsp     = lsn + 131072;             // T*B*N      = 131072
  int*   bar     = (int*)(lsp + 131072);     // 128 ints

  // time-parallel precompute
  ar_fill<<<640, 256, 0, stream>>>(mels, ar);
  w2t_fill<<<384, 256, 0, stream>>>(out_w2, w2t);
  bar_init<<<1, 128, 0, stream>>>(bar);

  // p1 = relu(ar @ w1^T)                 M=2048 N=256 K=80
  gemm_nt<<<dim3(4, 32), 256, 0, stream>>>(ar, DD, 0, prenet_w1, DD, 0,
                                           nullptr, nullptr, p1, 2048, PP, DD, 1, 0);
  // p2 = relu(p1 @ w2^T)                 M=2048 N=256 K=256
  gemm_nt<<<dim3(4, 32), 256, 0, stream>>>(p1, PP, 0, prenet_w2, PP, 0,
                                           nullptr, nullptr, p2, 2048, PP, PP, 1, 0);
  // gates_x = p2 @ w_ih^T + b_ih + b_hh  M=2048 N=2048 K=256
  gemm_nt<<<dim3(32, 32), 256, 0, stream>>>(p2, PP, 0, w_ih, PP, 0,
                                            b_ih, b_hh, gates_x, 2048, 2048, PP, 0, 0);
  // ziT = (inputs @ W1_e^T + b1), stored [b][o][n]   M=512 N=512 K=512
  gemm_nt<<<dim3(8, 8), 256, 0, stream>>>(inputs, 512, 0, out_w1, 1024, 512,
                                          out_b1, nullptr, ziT, 512, OO, 512, 0, 1);

  // sequential LSTM
  lstm_seq<<<128, 128, 0, stream>>>(w_hh, gates_x, h_all, bar);

  // hv = h_all @ W1_h^T                  M=2048 N=512 K=512
  gemm_nt<<<dim3(8, 32), 256, 0, stream>>>(h_all, HH, 0, out_w1, 1024, 0,
                                           nullptr, nullptr, hv, 2048, OO, HH, 0, 0);

  // fused output net + emission
  outnet<<<2048, 256, 0, stream>>>(hv, ziT, w2t, out_b2, mels, inputs_len,
                                   em, lsn, lsp);

  // sequential HMM scan
  hmm_scan<<<1, 512, 0, stream>>>(em, lsn, lsp, inputs_len, mel_lens, (float*)d_out);
}

// Round 2
// 1763.206 us; speedup vs baseline: 2.5933x; 2.5933x over previous
//
#include <hip/hip_runtime.h>
#include <math.h>

// Problem constants
#define T_STEPS 256
#define BB 8
#define NSTATE 64
#define DD 80
#define PP 256
#define HH 512
#define OO 512
#define NPARAM 161   // 2*D+1
#define NPADP 192    // padded param dim for LDS tiles
#define PLS 171      // padded row stride for params in LDS (bank spread)
#define NEG_INF_F (-1000000.0f)

// lstm config
#define LB 128       // lstm blocks (4 j-units each)
#define LT 256       // lstm threads per block
#define HSTR 516     // hl row stride (floats) — bank spread
#define WSTR 516     // wl row stride
#define RSTR 132     // red row stride

__device__ __forceinline__ float sigmoidf_(float x) { return 1.0f / (1.0f + __expf(-x)); }

// ---------------------------------------------------------------------------
// prep kernels
// ---------------------------------------------------------------------------
__global__ void ar_fill(const float* __restrict__ mels, float* __restrict__ ar) {
  int idx = blockIdx.x * 256 + threadIdx.x;
  if (idx >= T_STEPS * BB * DD) return;
  int d = idx % DD; int r = idx / DD; int b = r % BB; int t = r / BB;
  // ar[t][b][d] = t==0 ? 0 : mels[b][d][t-1]
  ar[idx] = (t == 0) ? 0.0f : mels[(b * DD + d) * T_STEPS + (t - 1)];
}

__global__ void w2t_fill(const float* __restrict__ w2, float* __restrict__ w2t) {
  int idx = blockIdx.x * 256 + threadIdx.x;
  if (idx >= OO * NPADP) return;
  int p = idx % NPADP; int k = idx / NPADP;
  w2t[idx] = (p < NPARAM) ? w2[p * OO + k] : 0.0f;  // w2t[k][p] = out_w2[p][k]
}

__global__ void bar_init(int* flags) {
  int i = blockIdx.x * 256 + threadIdx.x;
  if (i < LB * 16) flags[i] = 0;
}

// ---------------------------------------------------------------------------
// generic tiled fp32 GEMM:  C[m][n] = act( sum_k A[m][aoff+k]*B[n][boff+k] + bias )
// M,N multiples of 64. Grid (N/64, M/64), 256 threads, 4x4 per-thread tile.
// tstore=1: scatter-store for ziT layout [b][o][nstate] (M must be B*NSTATE, N=OO).
// ---------------------------------------------------------------------------
__global__ __launch_bounds__(256)
void gemm_nt(const float* __restrict__ A, int lda, int aoff,
             const float* __restrict__ Bw, int ldb, int boff,
             const float* __restrict__ bias1, const float* __restrict__ bias2,
             float* __restrict__ C, int M, int N, int K, int relu, int tstore)
{
  __shared__ float As[32][64];   // [kk][mm]
  __shared__ float Bs[32][64];   // [kk][nn]
  const int tid = threadIdx.x;
  const int m0 = blockIdx.y * 64, n0 = blockIdx.x * 64;
  const int tm = tid & 15, tn = tid >> 4;
  float acc[4][4] = {{0.f,0.f,0.f,0.f},{0.f,0.f,0.f,0.f},{0.f,0.f,0.f,0.f},{0.f,0.f,0.f,0.f}};

  for (int k0 = 0; k0 < K; k0 += 32) {
#pragma unroll
    for (int half = 0; half < 2; ++half) {
      int mm = (tid >> 3) + half * 32;
      int kk = (tid & 7) * 4;
      const float* ap = &A[(size_t)(m0 + mm) * lda + aoff + k0 + kk];
      float4 av;
      if (k0 + kk + 3 < K) {
        av = *(const float4*)ap;
      } else {
        av.x = (k0 + kk + 0 < K) ? ap[0] : 0.f;
        av.y = (k0 + kk + 1 < K) ? ap[1] : 0.f;
        av.z = (k0 + kk + 2 < K) ? ap[2] : 0.f;
        av.w = (k0 + kk + 3 < K) ? ap[3] : 0.f;
      }
      As[kk + 0][mm] = av.x; As[kk + 1][mm] = av.y;
      As[kk + 2][mm] = av.z; As[kk + 3][mm] = av.w;
      const float* bp = &Bw[(size_t)(n0 + mm) * ldb + boff + k0 + kk];
      float4 bv;
      if (k0 + kk + 3 < K) {
        bv = *(const float4*)bp;
      } else {
        bv.x = (k0 + kk + 0 < K) ? bp[0] : 0.f;
        bv.y = (k0 + kk + 1 < K) ? bp[1] : 0.f;
        bv.z = (k0 + kk + 2 < K) ? bp[2] : 0.f;
        bv.w = (k0 + kk + 3 < K) ? bp[3] : 0.f;
      }
      Bs[kk + 0][mm] = bv.x; Bs[kk + 1][mm] = bv.y;
      Bs[kk + 2][mm] = bv.z; Bs[kk + 3][mm] = bv.w;
    }
    __syncthreads();
#pragma unroll
    for (int kk = 0; kk < 32; ++kk) {
      float4 a4 = *(const float4*)&As[kk][tm * 4];
      float4 b4 = *(const float4*)&Bs[kk][tn * 4];
      float av[4] = {a4.x, a4.y, a4.z, a4.w};
      float bvv[4] = {b4.x, b4.y, b4.z, b4.w};
#pragma unroll
      for (int i = 0; i < 4; ++i)
#pragma unroll
        for (int j = 0; j < 4; ++j)
          acc[i][j] += av[i] * bvv[j];
    }
    __syncthreads();
  }

  float bj[4];
#pragma unroll
  for (int j = 0; j < 4; ++j) {
    int n = n0 + tn * 4 + j;
    float bv = 0.f;
    if (bias1) bv += bias1[n];
    if (bias2) bv += bias2[n];
    bj[j] = bv;
  }
  if (!tstore) {
#pragma unroll
    for (int i = 0; i < 4; ++i) {
      int m = m0 + tm * 4 + i;
      float4 v;
      v.x = acc[i][0] + bj[0]; v.y = acc[i][1] + bj[1];
      v.z = acc[i][2] + bj[2]; v.w = acc[i][3] + bj[3];
      if (relu) {
        v.x = fmaxf(v.x, 0.f); v.y = fmaxf(v.y, 0.f);
        v.z = fmaxf(v.z, 0.f); v.w = fmaxf(v.w, 0.f);
      }
      *(float4*)&C[(size_t)m * N + n0 + tn * 4] = v;
    }
  } else {
    // ziT[b][o][ns]: m = b*64+ns, n = o
#pragma unroll
    for (int i = 0; i < 4; ++i) {
      int m = m0 + tm * 4 + i;
      int bb = m >> 6, ns = m & 63;
#pragma unroll
      for (int j = 0; j < 4; ++j) {
        int o = n0 + tn * 4 + j;
        float v = acc[i][j] + bj[j];
        if (relu) v = fmaxf(v, 0.f);
        C[((size_t)bb * OO + o) * NSTATE + ns] = v;
      }
    }
  }
}

// ---------------------------------------------------------------------------
// persistent sequential LSTM v2: self-timed mailbox, no grid barrier.
// 128 blocks x 256 threads; block owns 4 h-units (16 gate-rows) x 8 batches.
// Per step: poll 128 per-producer flags with 64 lanes in parallel (1 RT),
// load h[t-1] (8B uncached atomics), tiled matvec (4r x 2b x k-slice per
// thread, float4 LDS), LDS k-reduction, c/h update, publish h + flag.
// Ordering: __syncthreads drains vmcnt (h stores at coherence point) before
// the relaxed flag store; consumer h-loads are issued only after the poll
// branch resolves (control dependency) + sched_barrier for compiler order.
// ---------------------------------------------------------------------------
__global__ __launch_bounds__(LT)
void lstm_seq(const float* __restrict__ w_hh, const float* __restrict__ gates_x,
              float* __restrict__ h_all, int* __restrict__ flags)
{
  __shared__ float wl[16][WSTR];   // 33.0 KB  rows r=g*4+jl
  __shared__ float hl[8][HSTR];    // 16.5 KB
  __shared__ float red[16][RSTR];  //  8.4 KB  [ksl][out]
  __shared__ float gl[128];        //  0.5 KB  [out] gate pre-activations
  const int tid = threadIdx.x;
  const int blk = blockIdx.x;
  const int j0 = blk * 4;

  // persistent: load w_hh slice once (rows g*512 + j0 + jl)
  for (int r = 0; r < 16; ++r) {
    int g = r >> 2, jl = r & 3;
    const float* src = &w_hh[((size_t)(g * HH + j0 + jl)) * HH];
    for (int k = tid; k < HH; k += LT) wl[r][k] = src[k];
  }

  const int rg  = tid >> 6;          // row group: rows rg*4..rg*4+3 (const per wave)
  const int bg  = (tid >> 4) & 3;    // batches 2bg, 2bg+1
  const int ksl = tid & 15;          // k chunks: k = ksl*4 + 64*i, i=0..7
  const int cjl = tid >> 3, cb = tid & 7;  // c-update mapping (tid<32)
  float c_reg = 0.f;

  for (int t = 0; t < T_STEPS; ++t) {
    // ---- acquire h[t-1] ----
    if (t == 0) {
      for (int i = tid; i < 8 * HSTR; i += LT) ((float*)hl)[i] = 0.f;
    } else {
      if (tid < 64) {
        for (;;) {
          int f0 = __hip_atomic_load(&flags[tid * 16], __ATOMIC_RELAXED, __HIP_MEMORY_SCOPE_AGENT);
          int f1 = __hip_atomic_load(&flags[(tid + 64) * 16], __ATOMIC_RELAXED, __HIP_MEMORY_SCOPE_AGENT);
          if (__all(f0 >= t && f1 >= t)) break;
          __builtin_amdgcn_s_sleep(1);
        }
      }
      __builtin_amdgcn_sched_barrier(0);
      __syncthreads();
      const double* hsrc = (const double*)(h_all + (size_t)(t - 1) * BB * HH);
#pragma unroll
      for (int q = 0; q < 4; ++q) {
        int i = tid + LT * q;           // float2 index: b = i>>8, j = (i&255)*2
        union { double d; float f[2]; } u;
        u.d = __hip_atomic_load(hsrc + i, __ATOMIC_RELAXED, __HIP_MEMORY_SCOPE_AGENT);
        int b = i >> 8, j = (i & 255) * 2;
        hl[b][j] = u.f[0]; hl[b][j + 1] = u.f[1];
      }
    }
    // prefetch gates_x (overlaps with barrier + compute)
    float gx = 0.f;
    if (tid < 128) {
      int r = tid >> 3, b = tid & 7, g = r >> 2, jl = r & 3;
      gx = gates_x[((size_t)t * BB + b) * (4 * HH) + g * HH + j0 + jl];
    }
    __syncthreads();

    // ---- partial matvec ----
    float acc[4][2] = {{0.f,0.f},{0.f,0.f},{0.f,0.f},{0.f,0.f}};
#pragma unroll
    for (int i = 0; i < 8; ++i) {
      const int k = ksl * 4 + 64 * i;
      float4 h0 = *(const float4*)&hl[bg * 2][k];
      float4 h1 = *(const float4*)&hl[bg * 2 + 1][k];
#pragma unroll
      for (int rl = 0; rl < 4; ++rl) {
        float4 w = *(const float4*)&wl[rg * 4 + rl][k];
        acc[rl][0] += w.x * h0.x + w.y * h0.y + w.z * h0.z + w.w * h0.w;
        acc[rl][1] += w.x * h1.x + w.y * h1.y + w.z * h1.z + w.w * h1.w;
      }
    }
#pragma unroll
    for (int rl = 0; rl < 4; ++rl) {
#pragma unroll
      for (int bl = 0; bl < 2; ++bl)
        red[ksl][(rg * 4 + rl) * 8 + bg * 2 + bl] = acc[rl][bl];
    }
    __syncthreads();

    // ---- k-reduction + bias ----
    if (tid < 128) {
      float s = gx;
#pragma unroll
      for (int p = 0; p < 16; ++p) s += red[p][tid];
      gl[tid] = s;
    }
    __syncthreads();

    // ---- c/h update + publish ----
    if (tid < 32) {
      float iv = gl[(0 * 4 + cjl) * 8 + cb];
      float fv = gl[(1 * 4 + cjl) * 8 + cb];
      float gv = gl[(2 * 4 + cjl) * 8 + cb];
      float ov = gl[(3 * 4 + cjl) * 8 + cb];
      float ct = sigmoidf_(fv) * c_reg + sigmoidf_(iv) * tanhf(gv);
      c_reg = ct;
      float h = sigmoidf_(ov) * tanhf(ct);
      __hip_atomic_store(&h_all[((size_t)t * BB + cb) * HH + j0 + cjl], h,
                         __ATOMIC_RELAXED, __HIP_MEMORY_SCOPE_AGENT);
    }
    __syncthreads();  // drains vmcnt: h stores at coherence point before flag
    if (tid == 0)
      __hip_atomic_store(&flags[blk * 16], t + 1, __ATOMIC_RELAXED, __HIP_MEMORY_SCOPE_AGENT);
  }
}

// ---------------------------------------------------------------------------
// fused output net + emission, block per (t,b):
// hid = relu(hv[t,b,:] + ziT[b,:,n]); params = hid @ w2t + b2;
// emission (Gaussian logpdf sum over D, masked), trans log-sigmoids.
// ---------------------------------------------------------------------------
__global__ __launch_bounds__(256)
void outnet(const float* __restrict__ hv, const float* __restrict__ ziT,
            const float* __restrict__ w2t, const float* __restrict__ b2,
            const float* __restrict__ mels, const int* __restrict__ inputs_len,
            float* __restrict__ em_out, float* __restrict__ lsn_out,
            float* __restrict__ lsp_out)
{
  __shared__ float smem[10944 + OO + DD];
  float* w2s = smem;            // [32][192] (union with pl)
  float* hs  = smem + 6144;     // [32][64]
  float* pl  = smem;            // [64][PLS] after GEMM loop
  float* hvs = smem + 10944;    // [512]
  float* xts = smem + 10944 + OO;  // [80]
  const int tid = threadIdx.x;
  const int tb = blockIdx.x;
  const int t = tb >> 3, b = tb & 7;

  if (tid < 128) *(float4*)&hvs[tid * 4] = *(const float4*)&hv[(size_t)tb * OO + tid * 4];
  if (tid < DD) xts[tid] = mels[(b * DD + tid) * T_STEPS + t];
  __syncthreads();

  const int tm = tid & 15, tn = tid >> 4;
  float acc[4][12];
#pragma unroll
  for (int i = 0; i < 4; ++i)
#pragma unroll
    for (int j = 0; j < 12; ++j) acc[i][j] = 0.f;

  for (int kc = 0; kc < 16; ++kc) {
    const int k0 = kc * 32;
    for (int i4 = tid; i4 < 1536; i4 += 256)
      *(float4*)&w2s[i4 * 4] = *(const float4*)&w2t[(size_t)k0 * NPADP + i4 * 4];
    const float* zsrc = ziT + (size_t)b * OO * NSTATE + (size_t)k0 * NSTATE;
    for (int i4 = tid; i4 < 512; i4 += 256) {
      float4 z = *(const float4*)&zsrc[i4 * 4];
      float hh = hvs[k0 + (i4 >> 4)];
      float4 r;
      r.x = fmaxf(z.x + hh, 0.f); r.y = fmaxf(z.y + hh, 0.f);
      r.z = fmaxf(z.z + hh, 0.f); r.w = fmaxf(z.w + hh, 0.f);
      *(float4*)&hs[i4 * 4] = r;
    }
    __syncthreads();
#pragma unroll
    for (int kk = 0; kk < 32; ++kk) {
      float4 a4 = *(const float4*)&hs[kk * 64 + tm * 4];
      float4 wa = *(const float4*)&w2s[kk * NPADP + tn * 12];
      float4 wb = *(const float4*)&w2s[kk * NPADP + tn * 12 + 4];
      float4 wc = *(const float4*)&w2s[kk * NPADP + tn * 12 + 8];
      float av[4]  = {a4.x, a4.y, a4.z, a4.w};
      float wv[12] = {wa.x, wa.y, wa.z, wa.w, wb.x, wb.y, wb.z, wb.w,
                      wc.x, wc.y, wc.z, wc.w};
#pragma unroll
      for (int i = 0; i < 4; ++i)
#pragma unroll
        for (int j = 0; j < 12; ++j)
          acc[i][j] += av[i] * wv[j];
    }
    __syncthreads();
  }

  // params -> LDS (union region; all GEMM reads done)
#pragma unroll
  for (int i = 0; i < 4; ++i)
#pragma unroll
    for (int j = 0; j < 12; ++j) {
      int p = tn * 12 + j;
      if (p < NPARAM) pl[(tm * 4 + i) * PLS + p] = acc[i][j] + b2[p];
    }
  __syncthreads();

  const int ne = tid >> 2, dq = tid & 3;
  float s = 0.f;
  for (int d = dq * 20; d < dq * 20 + 20; ++d) {
    float mean = pl[ne * PLS + d];
    float sp   = pl[ne * PLS + 80 + d];
    float x = xts[d];
    float sf = (sp > 20.f) ? sp : log1pf(__expf(sp));
    float sd = fmaxf(sf, 0.001f);
    float zz = (x - mean) / sd;
    s += -0.5f * zz * zz - __logf(sd) - 0.91893853320467274f;  // 0.5*log(2*pi)
  }
  s += __shfl_xor(s, 1);
  s += __shfl_xor(s, 2);
  if (dq == 0) {
    int ilen = inputs_len[b];
    em_out[(size_t)tb * NSTATE + ne] = (ne < ilen) ? s : 0.f;
    float tv = pl[ne * PLS + 160];
    lsp_out[(size_t)tb * NSTATE + ne] = __logf(fmaxf(sigmoidf_(tv), 1e-4f));
    lsn_out[(size_t)tb * NSTATE + ne] = __logf(fmaxf(sigmoidf_(-tv), 1e-4f));
  }
}

// ---------------------------------------------------------------------------
// sequential HMM forward scan: 1 block, wave per batch, alpha in registers.
// ---------------------------------------------------------------------------
__global__ __launch_bounds__(512)
void hmm_scan(const float* __restrict__ em, const float* __restrict__ lsn,
              const float* __restrict__ lsp, const int* __restrict__ inputs_len,
              const int* __restrict__ mel_lens, float* __restrict__ out)
{
  const int tid = threadIdx.x;
  const int b = tid >> 6, n = tid & 63;
  const int ilen = inputs_len[b], mlen = mel_lens[b];
  const bool mask = n < ilen;
  float alpha = 0.f, slc = 0.f, la = NEG_INF_F, llsp = 0.f;

  for (int t = 0; t < T_STEPS; ++t) {
    size_t base = ((size_t)t * BB + b) * NSTATE + n;
    float e = em[base], ln_ = lsn[base], lp_ = lsp[base];
    float at;
    if (t == 0) {
      at = ((n == 0) ? 0.f : NEG_INF_F) + e;
    } else {
      float stay = alpha + ln_;
      float lvs = alpha + lp_;
      float lv = __shfl_up(lvs, 1, 64);
      if (n == 0) lv = NEG_INF_F;
      float mx = fmaxf(stay, lv), mn = fminf(stay, lv);
      float tt = mask ? (mx + log1pf(__expf(mn - mx))) : NEG_INF_F;
      at = e + tt;
    }
    float m = at;
#pragma unroll
    for (int off = 1; off < 64; off <<= 1) m = fmaxf(m, __shfl_xor(m, off));
    float es = __expf(at - m);
#pragma unroll
    for (int off = 1; off < 64; off <<= 1) es += __shfl_xor(es, off);
    float logc = m + __logf(es);
    alpha = at - logc;
    if (t < mlen) slc += logc;
    if (t == mlen - 1) { la = mask ? alpha : NEG_INF_F; llsp = lp_; }
  }

  float v = la + ((n == ilen - 1) ? llsp : NEG_INF_F);
  float m = v;
#pragma unroll
  for (int off = 1; off < 64; off <<= 1) m = fmaxf(m, __shfl_xor(m, off));
  float es = __expf(v - m);
#pragma unroll
  for (int off = 1; off < 64; off <<= 1) es += __shfl_xor(es, off);
  float sfin = m + __logf(es);
  if (n == 0) out[b] = slc + sfin;
}

// ---------------------------------------------------------------------------
extern "C" void kernel_launch(void* const* d_in, const int* in_sizes, int n_in,
                              void* d_out, int out_size, void* d_ws, size_t ws_size,
                              hipStream_t stream)
{
  const float* inputs    = (const float*)d_in[0];
  const float* mels      = (const float*)d_in[1];
  const float* prenet_w1 = (const float*)d_in[2];
  const float* prenet_w2 = (const float*)d_in[3];
  const float* w_ih      = (const float*)d_in[4];
  const float* w_hh      = (const float*)d_in[5];
  const float* b_ih      = (const float*)d_in[6];
  const float* b_hh      = (const float*)d_in[7];
  const float* out_w1    = (const float*)d_in[8];
  const float* out_b1    = (const float*)d_in[9];
  const float* out_w2    = (const float*)d_in[10];
  const float* out_b2    = (const float*)d_in[11];
  const int* inputs_len  = (const int*)d_in[12];
  const int* mel_lens    = (const int*)d_in[13];

  float* ws = (float*)d_ws;
  float* ar      = ws;                       // T*B*D      = 163840
  float* p1      = ar + 163840;              // T*B*P      = 524288
  float* p2      = p1 + 524288;              // T*B*P      = 524288
  float* gates_x = p2 + 524288;              // T*B*4H     = 4194304
  float* ziT     = gates_x + 4194304;        // B*O*N      = 262144
  float* w2t     = ziT + 262144;             // O*NPADP    = 98304
  float* h_all   = w2t + 98304;              // T*B*H      = 1048576
  float* hv      = h_all + 1048576;          // T*B*O      = 1048576
  float* em      = hv + 1048576;             // T*B*N      = 131072
  float* lsn     = em + 131072;              // T*B*N      = 131072
  float* lsp     = lsn + 131072;             // T*B*N      = 131072
  int*   flags   = (int*)(lsp + 131072);     // LB*16 ints

  // time-parallel precompute
  ar_fill<<<640, 256, 0, stream>>>(mels, ar);
  w2t_fill<<<384, 256, 0, stream>>>(out_w2, w2t);
  bar_init<<<8, 256, 0, stream>>>(flags);

  // p1 = relu(ar @ w1^T)                 M=2048 N=256 K=80
  gemm_nt<<<dim3(4, 32), 256, 0, stream>>>(ar, DD, 0, prenet_w1, DD, 0,
                                           nullptr, nullptr, p1, 2048, PP, DD, 1, 0);
  // p2 = relu(p1 @ w2^T)                 M=2048 N=256 K=256
  gemm_nt<<<dim3(4, 32), 256, 0, stream>>>(p1, PP, 0, prenet_w2, PP, 0,
                                           nullptr, nullptr, p2, 2048, PP, PP, 1, 0);
  // gates_x = p2 @ w_ih^T + b_ih + b_hh  M=2048 N=2048 K=256
  gemm_nt<<<dim3(32, 32), 256, 0, stream>>>(p2, PP, 0, w_ih, PP, 0,
                                            b_ih, b_hh, gates_x, 2048, 2048, PP, 0, 0);
  // ziT = (inputs @ W1_e^T + b1), stored [b][o][n]   M=512 N=512 K=512
  gemm_nt<<<dim3(8, 8), 256, 0, stream>>>(inputs, 512, 0, out_w1, 1024, 512,
                                          out_b1, nullptr, ziT, 512, OO, 512, 0, 1);

  // sequential LSTM (self-timed mailbox)
  lstm_seq<<<LB, LT, 0, stream>>>(w_hh, gates_x, h_all, flags);

  // hv = h_all @ W1_h^T                  M=2048 N=512 K=512
  gemm_nt<<<dim3(8, 32), 256, 0, stream>>>(h_all, HH, 0, out_w1, 1024, 0,
                                           nullptr, nullptr, hv, 2048, OO, HH, 0, 0);

  // fused output net + emission
  outnet<<<2048, 256, 0, stream>>>(hv, ziT, w2t, out_b2, mels, inputs_len,
                                   em, lsn, lsp);

  // sequential HMM scan
  hmm_scan<<<1, 512, 0, stream>>>(em, lsn, lsp, inputs_len, mel_lens, (float*)d_out);
}